// Round 9
// baseline (125.672 us; speedup 1.0000x reference)
//
#include <hip/hip_runtime.h>
#include <math.h>

#define BLOCK 256

__device__ __forceinline__ float fast_rcp(float x) {
    return __builtin_amdgcn_rcpf(x);
}
__device__ __forceinline__ float fsin(float x) {
    return __builtin_amdgcn_sinf(x * 0.15915494309189535f);
}
__device__ __forceinline__ float fcos(float x) {
    return __builtin_amdgcn_cosf(x * 0.15915494309189535f);
}

// L1 "diamond" pseudo-angle: strictly monotone in atan2(y,x); (0,0) -> 0.
__device__ __forceinline__ float pseudo_angle(float x, float y) {
    float d = fabsf(x) + fabsf(y);
    float p = (d == 0.f) ? 1.f : x * fast_rcp(d);
    return (y < 0.f) ? (p - 1.f) : (1.f - p);
}

// Liang-Barsky clip of segment a->b against AABB [-hw,hw]x[-hh,hh];
// returns cross(pa,pb) of the clipped sub-segment (0 if empty).
__device__ __forceinline__ float seg_in_aabb_cross(float ax, float ay,
                                                   float bx, float by,
                                                   float hw, float hh) {
    float ex = bx - ax, ey = by - ay;
    float t0 = 0.f, t1 = 1.f;
    bool feas = true;
    {
        bool par = (ex == 0.f);
        float r = fast_rcp(ex);
        float ta = (hw - ax) * r, tb = (-hw - ax) * r;
        float tlo = fminf(ta, tb), thi = fmaxf(ta, tb);
        t0 = par ? t0 : fmaxf(t0, tlo);
        t1 = par ? t1 : fminf(t1, thi);
        feas = feas && (!par || (fabsf(ax) <= hw));
    }
    {
        bool par = (ey == 0.f);
        float r = fast_rcp(ey);
        float ta = (hh - ay) * r, tb = (-hh - ay) * r;
        float tlo = fminf(ta, tb), thi = fmaxf(ta, tb);
        t0 = par ? t0 : fmaxf(t0, tlo);
        t1 = par ? t1 : fminf(t1, thi);
        feas = feas && (!par || (fabsf(ay) <= hh));
    }
    bool valid = feas && (t1 > t0);
    float pax = fmaf(t0, ex, ax), pay = fmaf(t0, ey, ay);
    float pbx = fmaf(t1, ex, ax), pby = fmaf(t1, ey, ay);
    float cr = pax * pby - pay * pbx;
    return valid ? cr : 0.f;
}

// Clip segment a + t*e (t in [0,1]) against CCW convex quad (qx,qy);
// inside: cross(d_i, p - v_i) >= 0. Returns cross(pa,pb) of clipped part.
__device__ __forceinline__ float seg_in_quad_cross(float ax, float ay,
                                                   float ex, float ey,
                                                   const float* qx,
                                                   const float* qy) {
    float t0 = 0.f, t1 = 1.f;
    bool feas = true;
#pragma unroll
    for (int i = 0; i < 4; ++i) {
        int in_ = (i + 1) & 3;
        float dix = qx[in_] - qx[i], diy = qy[in_] - qy[i];
        float ga = dix * (ay - qy[i]) - diy * (ax - qx[i]);  // g(0)
        float gd = dix * ey - diy * ex;                      // dg/dt
        bool par = (gd == 0.f);
        float tk = -ga * fast_rcp(gd);
        t0 = (!par && gd > 0.f) ? fmaxf(t0, tk) : t0;
        t1 = (!par && gd < 0.f) ? fminf(t1, tk) : t1;
        feas = feas && (!par || (ga >= 0.f));
    }
    bool valid = feas && (t1 > t0);
    float pax = fmaf(t0, ex, ax), pay = fmaf(t0, ey, ay);
    float pbx = fmaf(t1, ex, ax), pby = fmaf(t1, ey, ay);
    float cr = pax * pby - pay * pbx;
    return valid ? cr : 0.f;
}

__launch_bounds__(BLOCK)
__global__ void giou_kernel(const float* __restrict__ pred,
                            const float* __restrict__ target,
                            const float* __restrict__ weight,
                            float* __restrict__ block_sums,
                            unsigned* __restrict__ counter,
                            float* __restrict__ out,
                            int N, int nblocks, float scale) {
    __shared__ float sacc[BLOCK / 64];
    __shared__ int is_last;

    int tid = threadIdx.x;
    long gi = (long)blockIdx.x * BLOCK + tid;
    int i = (gi < (long)N) ? (int)gi : (N - 1);

    float p[5], q[5];
#pragma unroll
    for (int j = 0; j < 5; ++j) p[j] = pred[i * 5 + j];
#pragma unroll
    for (int j = 0; j < 5; ++j) q[j] = target[i * 5 + j];
    float wgt = weight[i];

    // ---- box2's local frame (areas rotation-invariant) ----
    float cq = fcos(q[4]), sq = fsin(q[4]);
    float dang = p[4] - q[4];
    float cd = fcos(dang), sd = fsin(dang);
    float hw = 0.5f * q[2], hh = 0.5f * q[3];   // box2 = [-hw,hw]x[-hh,hh]
    float dxc = p[0] - q[0], dyc = p[1] - q[1];
    float tx = dxc * cq + dyc * sq;
    float ty = -dxc * sq + dyc * cq;
    float ax_ = 0.5f * p[2] * cd, ay_ = 0.5f * p[2] * sd;
    float bx_ = -0.5f * p[3] * sd, by_ = 0.5f * p[3] * cd;

    // box1 corners in frame, CCW
    float qx[4], qy[4];
    qx[0] = tx + ax_ + bx_; qy[0] = ty + ay_ + by_;
    qx[1] = tx - ax_ + bx_; qy[1] = ty - ay_ + by_;
    qx[2] = tx - ax_ - bx_; qy[2] = ty - ay_ - by_;
    qx[3] = tx + ax_ - bx_; qy[3] = ty + ay_ - by_;

    // ---- overlap via Green's theorem: 8 independent segment clips ----
    float s = 0.f;
    s += seg_in_aabb_cross(qx[0], qy[0], qx[1], qy[1], hw, hh);
    s += seg_in_aabb_cross(qx[1], qy[1], qx[2], qy[2], hw, hh);
    s += seg_in_aabb_cross(qx[2], qy[2], qx[3], qy[3], hw, hh);
    s += seg_in_aabb_cross(qx[3], qy[3], qx[0], qy[0], hw, hh);
    float w2 = hw + hw, h2 = hh + hh;
    s += seg_in_quad_cross(hw, -hh, 0.f, h2, qx, qy);
    s += seg_in_quad_cross(hw, hh, -w2, 0.f, qx, qy);
    s += seg_in_quad_cross(-hw, hh, 0.f, -h2, qx, qy);
    s += seg_in_quad_cross(-hw, -hh, w2, 0.f, qx, qy);
    float overlap = 0.5f * fabsf(s);

    // ---- enclose: 8 frame points, angle-sorted shoelace via Batcher-19 ----
    float enc;
    {
        float px8[8], py8[8];
#pragma unroll
        for (int j = 0; j < 4; ++j) { px8[j] = qx[j]; py8[j] = qy[j]; }
        px8[4] = hw;  py8[4] = hh;
        px8[5] = -hw; py8[5] = hh;
        px8[6] = -hw; py8[6] = -hh;
        px8[7] = hw;  py8[7] = -hh;
        float ex = 0.f, ey = 0.f;
#pragma unroll
        for (int j = 0; j < 8; ++j) { ex += px8[j]; ey += py8[j]; }
        float mx = ex * 0.125f, my = ey * 0.125f;
        float ang[8];
#pragma unroll
        for (int j = 0; j < 8; ++j) ang[j] = pseudo_angle(px8[j] - mx, py8[j] - my);

#define CE(I, J)                                                   \
        {                                                          \
            bool sw = ang[I] > ang[J];                             \
            float ta = sw ? ang[J] : ang[I];                       \
            float tb = sw ? ang[I] : ang[J];                       \
            ang[I] = ta; ang[J] = tb;                              \
            float txp = sw ? px8[J] : px8[I];                      \
            float typ = sw ? py8[J] : py8[I];                      \
            px8[J] = sw ? px8[I] : px8[J];                         \
            py8[J] = sw ? py8[I] : py8[J];                         \
            px8[I] = txp; py8[I] = typ;                            \
        }
        CE(0,1) CE(2,3) CE(4,5) CE(6,7)
        CE(0,2) CE(1,3) CE(4,6) CE(5,7)
        CE(1,2) CE(5,6)
        CE(0,4) CE(1,5) CE(2,6) CE(3,7)
        CE(2,4) CE(3,5)
        CE(1,2) CE(3,4) CE(5,6)
#undef CE

        float acc2 = 0.f;
#pragma unroll
        for (int k = 0; k < 8; ++k) {
            int kn = (k + 1) & 7;
            acc2 += px8[k] * py8[kn] - py8[k] * px8[kn];
        }
        enc = 0.5f * fabsf(acc2);
    }

    // ---- GIoU loss ----
    float area1 = p[2] * p[3];
    float area2 = q[2] * q[3];
    float uni = area1 + area2 - overlap + 1e-6f;
    float iou = fmaxf(overlap / uni, 1e-6f);
    float giou = iou - (enc - uni) / enc;
    float loss = (1.f - giou) * wgt;
    if (gi >= (long)N) loss = 0.f;

    // ---- block reduce: wave shuffle -> LDS -> block sum ----
#pragma unroll
    for (int off = 32; off > 0; off >>= 1)
        loss += __shfl_down(loss, off, 64);
    if ((tid & 63) == 0) sacc[tid >> 6] = loss;
    __syncthreads();

    // ---- single-pass final reduction: last-block-done pattern ----
    if (tid == 0) {
        float bsum = 0.f;
#pragma unroll
        for (int k = 0; k < BLOCK / 64; ++k) bsum += sacc[k];
        // release store (agent scope): visible across non-coherent XCD L2s
        __hip_atomic_store(&block_sums[blockIdx.x], bsum,
                           __ATOMIC_RELEASE, __HIP_MEMORY_SCOPE_AGENT);
        unsigned old = __hip_atomic_fetch_add(counter, 1u,
                                              __ATOMIC_ACQ_REL,
                                              __HIP_MEMORY_SCOPE_AGENT);
        is_last = (old == (unsigned)(nblocks - 1)) ? 1 : 0;
    }
    __syncthreads();

    if (is_last) {
        float t = 0.f;
        for (int j = tid; j < nblocks; j += BLOCK)
            t += __hip_atomic_load(&block_sums[j],
                                   __ATOMIC_RELAXED, __HIP_MEMORY_SCOPE_AGENT);
#pragma unroll
        for (int off = 32; off > 0; off >>= 1)
            t += __shfl_down(t, off, 64);
        if ((tid & 63) == 0) sacc[tid >> 6] = t;
        __syncthreads();
        if (tid == 0) {
            float tot = 0.f;
#pragma unroll
            for (int k = 0; k < BLOCK / 64; ++k) tot += sacc[k];
            out[0] = tot * scale;
        }
    }
}

extern "C" void kernel_launch(void* const* d_in, const int* in_sizes, int n_in,
                              void* d_out, int out_size, void* d_ws, size_t ws_size,
                              hipStream_t stream) {
    const float* pred   = (const float*)d_in[0];
    const float* target = (const float*)d_in[1];
    const float* weight = (const float*)d_in[2];
    float* out = (float*)d_out;
    int N = in_sizes[0] / 5;

    int nblocks = (N + BLOCK - 1) / BLOCK;
    float* block_sums = (float*)d_ws;
    // counter parked at 64 KiB into the workspace (far past block_sums)
    unsigned* counter = (unsigned*)((char*)d_ws + (64 << 10));

    hipMemsetAsync(counter, 0, sizeof(unsigned), stream);
    giou_kernel<<<nblocks, BLOCK, 0, stream>>>(pred, target, weight,
                                               block_sums, counter, out,
                                               N, nblocks, 1.0f / (float)N);
}

// Round 10
// 83.352 us; speedup vs baseline: 1.5077x; 1.5077x over previous
//
#include <hip/hip_runtime.h>
#include <math.h>

#define BLOCK 256

__device__ __forceinline__ float fast_rcp(float x) {
    return __builtin_amdgcn_rcpf(x);
}
__device__ __forceinline__ float fsin(float x) {
    return __builtin_amdgcn_sinf(x * 0.15915494309189535f);
}
__device__ __forceinline__ float fcos(float x) {
    return __builtin_amdgcn_cosf(x * 0.15915494309189535f);
}

// L1 "diamond" pseudo-angle: strictly monotone in atan2(y,x); (0,0) -> 0.
__device__ __forceinline__ float pseudo_angle(float x, float y) {
    float d = fabsf(x) + fabsf(y);
    float p = (d == 0.f) ? 1.f : x * fast_rcp(d);
    return (y < 0.f) ? (p - 1.f) : (1.f - p);
}

// Liang-Barsky clip of segment a->b against AABB [-hw,hw]x[-hh,hh];
// returns cross(pa,pb) of the clipped sub-segment (0 if empty).
__device__ __forceinline__ float seg_in_aabb_cross(float ax, float ay,
                                                   float bx, float by,
                                                   float hw, float hh) {
    float ex = bx - ax, ey = by - ay;
    float t0 = 0.f, t1 = 1.f;
    bool feas = true;
    {
        bool par = (ex == 0.f);
        float r = fast_rcp(ex);
        float ta = (hw - ax) * r, tb = (-hw - ax) * r;
        float tlo = fminf(ta, tb), thi = fmaxf(ta, tb);
        t0 = par ? t0 : fmaxf(t0, tlo);
        t1 = par ? t1 : fminf(t1, thi);
        feas = feas && (!par || (fabsf(ax) <= hw));
    }
    {
        bool par = (ey == 0.f);
        float r = fast_rcp(ey);
        float ta = (hh - ay) * r, tb = (-hh - ay) * r;
        float tlo = fminf(ta, tb), thi = fmaxf(ta, tb);
        t0 = par ? t0 : fmaxf(t0, tlo);
        t1 = par ? t1 : fminf(t1, thi);
        feas = feas && (!par || (fabsf(ay) <= hh));
    }
    bool valid = feas && (t1 > t0);
    float pax = fmaf(t0, ex, ax), pay = fmaf(t0, ey, ay);
    float pbx = fmaf(t1, ex, ax), pby = fmaf(t1, ey, ay);
    float cr = pax * pby - pay * pbx;
    return valid ? cr : 0.f;
}

// Clip segment a + t*e (t in [0,1]) against CCW convex quad (qx,qy);
// inside: cross(d_i, p - v_i) >= 0. Returns cross(pa,pb) of clipped part.
__device__ __forceinline__ float seg_in_quad_cross(float ax, float ay,
                                                   float ex, float ey,
                                                   const float* qx,
                                                   const float* qy) {
    float t0 = 0.f, t1 = 1.f;
    bool feas = true;
#pragma unroll
    for (int i = 0; i < 4; ++i) {
        int in_ = (i + 1) & 3;
        float dix = qx[in_] - qx[i], diy = qy[in_] - qy[i];
        float ga = dix * (ay - qy[i]) - diy * (ax - qx[i]);  // g(0)
        float gd = dix * ey - diy * ex;                      // dg/dt
        bool par = (gd == 0.f);
        float tk = -ga * fast_rcp(gd);
        t0 = (!par && gd > 0.f) ? fmaxf(t0, tk) : t0;
        t1 = (!par && gd < 0.f) ? fminf(t1, tk) : t1;
        feas = feas && (!par || (ga >= 0.f));
    }
    bool valid = feas && (t1 > t0);
    float pax = fmaf(t0, ex, ax), pay = fmaf(t0, ey, ay);
    float pbx = fmaf(t1, ex, ax), pby = fmaf(t1, ey, ay);
    float cr = pax * pby - pay * pbx;
    return valid ? cr : 0.f;
}

__launch_bounds__(BLOCK)
__global__ void giou_kernel(const float* __restrict__ pred,
                            const float* __restrict__ target,
                            const float* __restrict__ weight,
                            float* __restrict__ partials, int N) {
    // Coalesced staging: block slab = BLOCK*5 = 1280 contiguous floats per
    // array, loaded as 320 float4 (every byte used), then per-thread 5-float
    // reads from LDS (stride-5 -> 2 lanes/bank across wave64 = free).
    __shared__ float ldsP[BLOCK * 5];
    __shared__ float ldsQ[BLOCK * 5];

    int tid = threadIdx.x;
    long gi = (long)blockIdx.x * BLOCK + tid;
    int lim = N * 5;
    int base = blockIdx.x * (BLOCK * 5);

#pragma unroll
    for (int k = 0; k < (BLOCK * 5 / 4); k += BLOCK) {
        int kk = k + tid;
        if (kk < (BLOCK * 5 / 4)) {
            int off = base + 4 * kk;
            float4 vp, vq;
            if (off + 3 < lim) {
                vp = *(const float4*)(pred + off);
                vq = *(const float4*)(target + off);
            } else {
                int o0 = min(off, lim - 1), o1 = min(off + 1, lim - 1);
                int o2 = min(off + 2, lim - 1), o3 = min(off + 3, lim - 1);
                vp = make_float4(pred[o0], pred[o1], pred[o2], pred[o3]);
                vq = make_float4(target[o0], target[o1], target[o2], target[o3]);
            }
            ((float4*)ldsP)[kk] = vp;
            ((float4*)ldsQ)[kk] = vq;
        }
    }
    __syncthreads();

    float p[5], q[5];
#pragma unroll
    for (int j = 0; j < 5; ++j) p[j] = ldsP[tid * 5 + j];
#pragma unroll
    for (int j = 0; j < 5; ++j) q[j] = ldsQ[tid * 5 + j];
    int wi = (gi < (long)N) ? (int)gi : (N - 1);
    float wgt = weight[wi];   // stride-4B: already perfectly coalesced

    // ---- box2's local frame (areas rotation-invariant) ----
    float cq = fcos(q[4]), sq = fsin(q[4]);
    float dang = p[4] - q[4];
    float cd = fcos(dang), sd = fsin(dang);
    float hw = 0.5f * q[2], hh = 0.5f * q[3];   // box2 = [-hw,hw]x[-hh,hh]
    float dxc = p[0] - q[0], dyc = p[1] - q[1];
    float tx = dxc * cq + dyc * sq;
    float ty = -dxc * sq + dyc * cq;
    float ax_ = 0.5f * p[2] * cd, ay_ = 0.5f * p[2] * sd;
    float bx_ = -0.5f * p[3] * sd, by_ = 0.5f * p[3] * cd;

    // box1 corners in frame, CCW
    float qx[4], qy[4];
    qx[0] = tx + ax_ + bx_; qy[0] = ty + ay_ + by_;
    qx[1] = tx - ax_ + bx_; qy[1] = ty - ay_ + by_;
    qx[2] = tx - ax_ - bx_; qy[2] = ty - ay_ - by_;
    qx[3] = tx + ax_ - bx_; qy[3] = ty + ay_ - by_;

    // ---- overlap via Green's theorem: 8 independent segment clips ----
    float s = 0.f;
    s += seg_in_aabb_cross(qx[0], qy[0], qx[1], qy[1], hw, hh);
    s += seg_in_aabb_cross(qx[1], qy[1], qx[2], qy[2], hw, hh);
    s += seg_in_aabb_cross(qx[2], qy[2], qx[3], qy[3], hw, hh);
    s += seg_in_aabb_cross(qx[3], qy[3], qx[0], qy[0], hw, hh);
    float w2 = hw + hw, h2 = hh + hh;
    s += seg_in_quad_cross(hw, -hh, 0.f, h2, qx, qy);
    s += seg_in_quad_cross(hw, hh, -w2, 0.f, qx, qy);
    s += seg_in_quad_cross(-hw, hh, 0.f, -h2, qx, qy);
    s += seg_in_quad_cross(-hw, -hh, w2, 0.f, qx, qy);
    float overlap = 0.5f * fabsf(s);

    // ---- enclose: 8 frame points, angle-sorted shoelace via Batcher-19 ----
    float enc;
    {
        float px8[8], py8[8];
#pragma unroll
        for (int j = 0; j < 4; ++j) { px8[j] = qx[j]; py8[j] = qy[j]; }
        px8[4] = hw;  py8[4] = hh;
        px8[5] = -hw; py8[5] = hh;
        px8[6] = -hw; py8[6] = -hh;
        px8[7] = hw;  py8[7] = -hh;
        float ex = 0.f, ey = 0.f;
#pragma unroll
        for (int j = 0; j < 8; ++j) { ex += px8[j]; ey += py8[j]; }
        float mx = ex * 0.125f, my = ey * 0.125f;
        float ang[8];
#pragma unroll
        for (int j = 0; j < 8; ++j) ang[j] = pseudo_angle(px8[j] - mx, py8[j] - my);

#define CE(I, J)                                                   \
        {                                                          \
            bool sw = ang[I] > ang[J];                             \
            float ta = sw ? ang[J] : ang[I];                       \
            float tb = sw ? ang[I] : ang[J];                       \
            ang[I] = ta; ang[J] = tb;                              \
            float txp = sw ? px8[J] : px8[I];                      \
            float typ = sw ? py8[J] : py8[I];                      \
            px8[J] = sw ? px8[I] : px8[J];                         \
            py8[J] = sw ? py8[I] : py8[J];                         \
            px8[I] = txp; py8[I] = typ;                            \
        }
        CE(0,1) CE(2,3) CE(4,5) CE(6,7)
        CE(0,2) CE(1,3) CE(4,6) CE(5,7)
        CE(1,2) CE(5,6)
        CE(0,4) CE(1,5) CE(2,6) CE(3,7)
        CE(2,4) CE(3,5)
        CE(1,2) CE(3,4) CE(5,6)
#undef CE

        float acc2 = 0.f;
#pragma unroll
        for (int k = 0; k < 8; ++k) {
            int kn = (k + 1) & 7;
            acc2 += px8[k] * py8[kn] - py8[k] * px8[kn];
        }
        enc = 0.5f * fabsf(acc2);
    }

    // ---- GIoU loss ----
    float area1 = p[2] * p[3];
    float area2 = q[2] * q[3];
    float uni = area1 + area2 - overlap + 1e-6f;
    float iou = fmaxf(overlap / uni, 1e-6f);
    float giou = iou - (enc - uni) / enc;
    float loss = (1.f - giou) * wgt;
    if (gi >= (long)N) loss = 0.f;   // select also kills any tail-garbage NaN

    // wave-64 reduce -> one plain store per wave (no global atomics)
#pragma unroll
    for (int off = 32; off > 0; off >>= 1)
        loss += __shfl_down(loss, off, 64);
    if ((tid & 63) == 0)
        partials[blockIdx.x * (BLOCK / 64) + (tid >> 6)] = loss;
}

// Deterministic final reduce: one 1024-thread block over the partials.
__launch_bounds__(1024)
__global__ void reduce_kernel(const float* __restrict__ partials,
                              float* __restrict__ out, int nparts, float scale) {
    __shared__ float acc[16];
    int tid = threadIdx.x;
    float s = 0.f;
    for (int j = tid; j < nparts; j += 1024) s += partials[j];
#pragma unroll
    for (int off = 32; off > 0; off >>= 1)
        s += __shfl_down(s, off, 64);
    if ((tid & 63) == 0) acc[tid >> 6] = s;
    __syncthreads();
    if (tid == 0) {
        float t = 0.f;
#pragma unroll
        for (int k = 0; k < 16; ++k) t += acc[k];
        out[0] = t * scale;
    }
}

extern "C" void kernel_launch(void* const* d_in, const int* in_sizes, int n_in,
                              void* d_out, int out_size, void* d_ws, size_t ws_size,
                              hipStream_t stream) {
    const float* pred   = (const float*)d_in[0];
    const float* target = (const float*)d_in[1];
    const float* weight = (const float*)d_in[2];
    float* out = (float*)d_out;
    float* ws  = (float*)d_ws;
    int N = in_sizes[0] / 5;

    int nblocks = (N + BLOCK - 1) / BLOCK;
    int nparts = nblocks * (BLOCK / 64);
    giou_kernel<<<nblocks, BLOCK, 0, stream>>>(pred, target, weight, ws, N);
    reduce_kernel<<<1, 1024, 0, stream>>>(ws, out, nparts, 1.0f / (float)N);
}